// Round 1
// baseline (249.347 us; speedup 1.0000x reference)
//
#include <hip/hip_runtime.h>

typedef __bf16 bf16_t;
typedef __bf16 bf16x8 __attribute__((ext_vector_type(8)));
typedef float  f32x4  __attribute__((ext_vector_type(4)));

#define MFMA16(a, b, c) __builtin_amdgcn_mfma_f32_16x16x32_bf16((a), (b), (c), 0, 0, 0)

__device__ __forceinline__ float exp2_f(float x) { return __builtin_amdgcn_exp2f(x); }
__device__ __forceinline__ float log2_f(float x) { return __builtin_amdgcn_logf(x); }

union BPack { bf16_t h[2]; unsigned u; };

constexpr int Bn = 4, Cc = 128, Nn = 4096, NH = 4, DK = 32;
// fold 1/sqrt(32) * log2(e) into stored Q so MFMA emits exp2-domain logits
constexpr float QSCALE = 0.176776695f * 1.44269504f;

// ---------------------------------------------------------------------------
// K1: fused transpose + QKV projection.
//   xs[n][c] = x[b][c][n]   (staged bf16 in LDS, XOR-swizzled)
//   qkv = xs @ Wp^T + bp    (one head's 96 outputs per block.z)
//   q -> q_s[bh][n][d] * QSCALE ; k -> k_s[bh][n][d]
//   v -> vt_s[bh][d][J] transposed, with pair-interleave permutation
//        J: stored value at J is V[p(J)], p(J)=(J&~31)+((J&31)>>1)+((J&1)*16)
// ---------------------------------------------------------------------------
__global__ __launch_bounds__(256) void k_qkv(const float* __restrict__ x,
                                             const float* __restrict__ Wp,
                                             const float* __restrict__ bp,
                                             bf16_t* __restrict__ q_s,
                                             bf16_t* __restrict__ k_s,
                                             bf16_t* __restrict__ vt_s)
{
    __shared__ __attribute__((aligned(16))) char smem[40960]; // xs 16KB + wp 24KB
    const int n0 = blockIdx.x * 64;
    const int b  = blockIdx.y;
    const int h  = blockIdx.z;
    const int t  = threadIdx.x;
    const int w = t >> 6, lane = t & 63, a = lane & 15, g = lane >> 4;

    const float* xb = x + (size_t)b * Cc * Nn;
    // stage xs[64][128] bf16 (swizzled): xs[n][c] = x[b][c][n0+n]
    #pragma unroll
    for (int it = 0; it < 16; ++it) {
        int c = ((t >> 6) + it * 4) * 2;
        int n = t & 63;
        BPack p;
        p.h[0] = (bf16_t)xb[(size_t)c * Nn + n0 + n];
        p.h[1] = (bf16_t)xb[(size_t)(c + 1) * Nn + n0 + n];
        unsigned byte = n * 256 + ((unsigned)(c * 2) ^ ((n & 7) << 4));
        *(unsigned*)(smem + byte) = p.u;
    }
    // stage wp[96][128] bf16 (swizzled): wp[p][c] = Wp[h*96+p][c]
    const float* wpg = Wp + (size_t)h * 96 * Cc;
    #pragma unroll
    for (int it = 0; it < 24; ++it) {
        int idx = t + it * 256;
        int row = idx >> 6;
        int col = (idx & 63) * 2;
        BPack p;
        p.h[0] = (bf16_t)wpg[row * Cc + col];
        p.h[1] = (bf16_t)wpg[row * Cc + col + 1];
        unsigned byte = 16384 + row * 256 + ((unsigned)(col * 2) ^ ((row & 7) << 4));
        *(unsigned*)(smem + byte) = p.u;
    }
    __syncthreads();

    f32x4 acc[6] = {};
    #pragma unroll
    for (int kc = 0; kc < 4; ++kc) {
        int cb = (kc * 32 + g * 8) * 2;
        int rowA = w * 16 + a;
        bf16x8 af = *(const bf16x8*)(smem + rowA * 256 + (cb ^ ((rowA & 7) << 4)));
        #pragma unroll
        for (int pt = 0; pt < 6; ++pt) {
            int rowB = pt * 16 + a;
            bf16x8 bfr = *(const bf16x8*)(smem + 16384 + rowB * 256 + (cb ^ ((rowB & 7) << 4)));
            acc[pt] = MFMA16(af, bfr, acc[pt]);
        }
    }

    const int bh = b * NH + h;
    // q (tiles 0,1) and k (tiles 2,3): D layout col=a, row=g*4+r
    #pragma unroll
    for (int pt = 0; pt < 4; ++pt) {
        const int which = pt >> 1;
        const int d = (pt & 1) * 16 + a;
        const float bias = bp[h * 96 + which * 32 + d];
        bf16_t* dst = which ? k_s : q_s;
        const float sc = which ? 1.0f : QSCALE;
        #pragma unroll
        for (int r = 0; r < 4; ++r) {
            int n = n0 + w * 16 + g * 4 + r;
            dst[((size_t)bh * Nn + n) * DK + d] = (bf16_t)((acc[pt][r] + bias) * sc);
        }
    }
    __syncthreads();      // all waves done reading xs/wp
    // v tiles (4,5) -> transposed LDS [32][72]
    bf16_t* vt_l = (bf16_t*)smem;
    #pragma unroll
    for (int pt = 4; pt < 6; ++pt) {
        const int d = (pt & 1) * 16 + a;
        const float bias = bp[h * 96 + 64 + d];
        #pragma unroll
        for (int r = 0; r < 4; ++r) {
            int nl = w * 16 + g * 4 + r;
            vt_l[d * 72 + nl] = (bf16_t)(acc[pt][r] + bias);
        }
    }
    __syncthreads();
    // coalesced copy-out of V^T with pair-interleave permutation within 32-blocks
    #pragma unroll
    for (int it = 0; it < 8; ++it) {
        int idx = t + it * 256;
        int d = idx >> 6, n = idx & 63;
        int m = n & 31;
        int col = ((m & 15) << 1) | (m >> 4);
        int jj = (n & 32) | col;
        vt_s[((size_t)bh * DK + d) * Nn + n0 + jj] = vt_l[d * 72 + n];
    }
}

// ---------------------------------------------------------------------------
// K2: column stats. c[j] = log2( sum_i 2^t[i,j] ), t = QK^T in exp2 domain.
// Wave owns 32 j (two 16-col tiles), streams all i in 16-row chunks. No LDS.
// ---------------------------------------------------------------------------
__global__ __launch_bounds__(256) void k_stats(const bf16_t* __restrict__ q_s,
                                               const bf16_t* __restrict__ k_s,
                                               float* __restrict__ c_j)
{
    const int bh = blockIdx.x >> 5;
    const int j0 = (blockIdx.x & 31) * 128;
    const int t = threadIdx.x, w = t >> 6, lane = t & 63, a = lane & 15, g = lane >> 4;
    const bf16_t* Q = q_s + (size_t)bh * Nn * DK;
    const bf16_t* K = k_s + (size_t)bh * Nn * DK;
    const int jb = j0 + w * 32;
    bf16x8 kf0 = *(const bf16x8*)(K + (jb + a) * DK + g * 8);
    bf16x8 kf1 = *(const bf16x8*)(K + (jb + 16 + a) * DK + g * 8);
    f32x4 l0 = {}, l1 = {};
    #pragma unroll 4
    for (int i0 = 0; i0 < Nn; i0 += 16) {
        bf16x8 qf = *(const bf16x8*)(Q + (i0 + a) * DK + g * 8);
        f32x4 z = {};
        f32x4 t0 = MFMA16(qf, kf0, z);
        f32x4 t1 = MFMA16(qf, kf1, z);
        #pragma unroll
        for (int r = 0; r < 4; ++r) {
            l0[r] += exp2_f(t0[r]);
            l1[r] += exp2_f(t1[r]);
        }
    }
    float s0 = l0[0] + l0[1] + l0[2] + l0[3];
    float s1 = l1[0] + l1[1] + l1[2] + l1[3];
    s0 += __shfl_xor(s0, 16);
    s0 += __shfl_xor(s0, 32);
    s1 += __shfl_xor(s1, 16);
    s1 += __shfl_xor(s1, 32);
    if (g == 0) {
        c_j[(size_t)bh * Nn + jb + a]      = log2_f(s0);
        c_j[(size_t)bh * Nn + jb + 16 + a] = log2_f(s1);
    }
}

// ---------------------------------------------------------------------------
// K3: O[i,d] = sum_j 2^(t[i,j]-c[j]) * V[j,d].  Wave owns 32 i; streams j in
// 32-chunks. P goes D-layout -> (per-wave LDS, b32-packed, j pair-permuted to
// match vt_s) -> A-fragment. MFMA K-order permutation cancels between P and Vt.
// ---------------------------------------------------------------------------
__global__ __launch_bounds__(256) void k_attn(const bf16_t* __restrict__ q_s,
                                              const bf16_t* __restrict__ k_s,
                                              const bf16_t* __restrict__ vt_s,
                                              const float* __restrict__ c_j,
                                              bf16_t* __restrict__ res)
{
    __shared__ __attribute__((aligned(16))) bf16_t p_lds[4][32][40];
    const int bh = blockIdx.x >> 5;
    const int b = bh >> 2, h = bh & 3;
    const int i0 = (blockIdx.x & 31) * 128;
    const int t = threadIdx.x, w = t >> 6, lane = t & 63, a = lane & 15, g = lane >> 4;
    const bf16_t* Q  = q_s  + (size_t)bh * Nn * DK;
    const bf16_t* K  = k_s  + (size_t)bh * Nn * DK;
    const bf16_t* Vt = vt_s + (size_t)bh * DK * Nn;
    const float*  C  = c_j  + (size_t)bh * Nn;
    const int ib = i0 + w * 32;
    bf16x8 qf0 = *(const bf16x8*)(Q + (ib + a) * DK + g * 8);
    bf16x8 qf1 = *(const bf16x8*)(Q + (ib + 16 + a) * DK + g * 8);
    f32x4 o00 = {}, o01 = {}, o10 = {}, o11 = {};
    for (int j0 = 0; j0 < Nn; j0 += 32) {
        bf16x8 kf0 = *(const bf16x8*)(K + (j0 + a) * DK + g * 8);
        bf16x8 kf1 = *(const bf16x8*)(K + (j0 + 16 + a) * DK + g * 8);
        float c0 = C[j0 + a], c1 = C[j0 + 16 + a];
        f32x4 z = {};
        f32x4 s00 = MFMA16(qf0, kf0, z);
        f32x4 s01 = MFMA16(qf0, kf1, z);
        f32x4 s10 = MFMA16(qf1, kf0, z);
        f32x4 s11 = MFMA16(qf1, kf1, z);
        #pragma unroll
        for (int r = 0; r < 4; ++r) {
            BPack pA; pA.h[0] = (bf16_t)exp2_f(s00[r] - c0); pA.h[1] = (bf16_t)exp2_f(s01[r] - c1);
            *(unsigned*)&p_lds[w][g * 4 + r][2 * a] = pA.u;
            BPack pB; pB.h[0] = (bf16_t)exp2_f(s10[r] - c0); pB.h[1] = (bf16_t)exp2_f(s11[r] - c1);
            *(unsigned*)&p_lds[w][16 + g * 4 + r][2 * a] = pB.u;
        }
        bf16x8 pa0 = *(const bf16x8*)&p_lds[w][a][g * 8];
        bf16x8 pa1 = *(const bf16x8*)&p_lds[w][16 + a][g * 8];
        bf16x8 vf0 = *(const bf16x8*)(Vt + (size_t)a * Nn + j0 + g * 8);
        bf16x8 vf1 = *(const bf16x8*)(Vt + (size_t)(16 + a) * Nn + j0 + g * 8);
        o00 = MFMA16(pa0, vf0, o00);
        o01 = MFMA16(pa0, vf1, o01);
        o10 = MFMA16(pa1, vf0, o10);
        o11 = MFMA16(pa1, vf1, o11);
    }
    #pragma unroll
    for (int r = 0; r < 4; ++r) {
        int n0a = i0 + w * 32 + g * 4 + r;
        int n1a = n0a + 16;
        size_t base0 = ((size_t)b * Nn + n0a) * 128 + h * DK;
        size_t base1 = ((size_t)b * Nn + n1a) * 128 + h * DK;
        res[base0 + a]      = (bf16_t)o00[r];
        res[base0 + 16 + a] = (bf16_t)o01[r];
        res[base1 + a]      = (bf16_t)o10[r];
        res[base1 + 16 + a] = (bf16_t)o11[r];
    }
}

// ---------------------------------------------------------------------------
// K4: out[b][c][n] = (res @ Wo^T)[n][c] + bo[c] + x[b][c][n]
// LDS-staged bf16 Wo (swizzled) + LDS transpose of the output tile.
// ---------------------------------------------------------------------------
__global__ __launch_bounds__(256) void k_out(const bf16_t* __restrict__ res,
                                             const float* __restrict__ Wo,
                                             const float* __restrict__ bo,
                                             const float* __restrict__ x,
                                             float* __restrict__ out)
{
    __shared__ __attribute__((aligned(16))) char smem[33280]; // Wo bf16 32KB, then out_t [128][65] f32
    const int n0 = blockIdx.x * 64;
    const int b = blockIdx.y;
    const int t = threadIdx.x, w = t >> 6, lane = t & 63, a = lane & 15, g = lane >> 4;
    #pragma unroll
    for (int it = 0; it < 32; ++it) {
        int idx = t + it * 256;
        int row = idx >> 6;
        int col = (idx & 63) * 2;
        BPack p;
        p.h[0] = (bf16_t)Wo[row * 128 + col];
        p.h[1] = (bf16_t)Wo[row * 128 + col + 1];
        unsigned byte = row * 256 + ((unsigned)(col * 2) ^ ((row & 7) << 4));
        *(unsigned*)(smem + byte) = p.u;
    }
    __syncthreads();
    f32x4 acc[8] = {};
    #pragma unroll
    for (int kc = 0; kc < 4; ++kc) {
        int cb = (kc * 32 + g * 8) * 2;
        bf16x8 af = *(const bf16x8*)(res + ((size_t)b * Nn + n0 + w * 16 + a) * 128 + kc * 32 + g * 8);
        #pragma unroll
        for (int ct = 0; ct < 8; ++ct) {
            int rowB = ct * 16 + a;
            bf16x8 bfr = *(const bf16x8*)(smem + rowB * 256 + (cb ^ ((rowB & 7) << 4)));
            acc[ct] = MFMA16(af, bfr, acc[ct]);
        }
    }
    __syncthreads();
    float* out_t = (float*)smem;   // [128][65]
    #pragma unroll
    for (int ct = 0; ct < 8; ++ct) {
        int c = ct * 16 + a;
        #pragma unroll
        for (int r = 0; r < 4; ++r) {
            out_t[c * 65 + w * 16 + g * 4 + r] = acc[ct][r];
        }
    }
    __syncthreads();
    const float* xb = x + (size_t)b * Cc * Nn;
    #pragma unroll
    for (int it = 0; it < 32; ++it) {
        int idx = t + it * 256;
        int c = idx >> 6, n = idx & 63;
        out[((size_t)b * Cc + c) * Nn + n0 + n] = out_t[c * 65 + n] + xb[(size_t)c * Nn + n0 + n] + bo[c];
    }
}

extern "C" void kernel_launch(void* const* d_in, const int* in_sizes, int n_in,
                              void* d_out, int out_size, void* d_ws, size_t ws_size,
                              hipStream_t stream)
{
    const float* x  = (const float*)d_in[0];
    const float* Wp = (const float*)d_in[1];
    const float* bp = (const float*)d_in[2];
    const float* Wo = (const float*)d_in[3];
    const float* bo = (const float*)d_in[4];
    float* out = (float*)d_out;

    char* ws = (char*)d_ws;
    bf16_t* q_s  = (bf16_t*)(ws);                 // 4 MB
    bf16_t* k_s  = (bf16_t*)(ws + (4  << 20));    // 4 MB
    bf16_t* vt_s = (bf16_t*)(ws + (8  << 20));    // 4 MB
    bf16_t* res  = (bf16_t*)(ws + (12 << 20));    // 4 MB
    float*  c_j  = (float*) (ws + (16 << 20));    // 256 KB

    k_qkv  <<<dim3(Nn / 64, Bn, NH), 256, 0, stream>>>(x, Wp, bp, q_s, k_s, vt_s);
    k_stats<<<16 * (Nn / 128),      256, 0, stream>>>(q_s, k_s, c_j);
    k_attn <<<16 * (Nn / 128),      256, 0, stream>>>(q_s, k_s, vt_s, c_j, res);
    k_out  <<<dim3(Nn / 64, Bn),    256, 0, stream>>>(res, Wo, bo, x, out);
}

// Round 3
// 230.794 us; speedup vs baseline: 1.0804x; 1.0804x over previous
//
#include <hip/hip_runtime.h>

typedef __bf16 bf16_t;
typedef __bf16 bf16x8 __attribute__((ext_vector_type(8)));
typedef float  f32x4  __attribute__((ext_vector_type(4)));

#define MFMA16(a, b, c) __builtin_amdgcn_mfma_f32_16x16x32_bf16((a), (b), (c), 0, 0, 0)

__device__ __forceinline__ float exp2_f(float x) { return __builtin_amdgcn_exp2f(x); }

union BPack { bf16_t h[2]; unsigned u; };

constexpr int Bn = 4, Cc = 128, Nn = 4096, NH = 4, DK = 32;
// fold 1/sqrt(32) * log2(e) into stored Q so MFMA emits exp2-domain logits
constexpr float QSCALE = 0.176776695f * 1.44269504f;

// ---------------------------------------------------------------------------
// K1: fused transpose + QKV projection.
//   v -> vt_s[bh][d][J] transposed; stored value at J is V[p(J)],
//   p(J)=(J&~31)+((J&31)>>1)+((J&1)*16)  (5-bit rotate-right within 32-blocks)
// ---------------------------------------------------------------------------
__global__ __launch_bounds__(256) void k_qkv(const float* __restrict__ x,
                                             const float* __restrict__ Wp,
                                             const float* __restrict__ bp,
                                             bf16_t* __restrict__ q_s,
                                             bf16_t* __restrict__ k_s,
                                             bf16_t* __restrict__ vt_s)
{
    __shared__ __attribute__((aligned(16))) char smem[40960]; // xs 16KB + wp 24KB
    const int n0 = blockIdx.x * 64;
    const int b  = blockIdx.y;
    const int h  = blockIdx.z;
    const int t  = threadIdx.x;
    const int w = t >> 6, lane = t & 63, a = lane & 15, g = lane >> 4;

    const float* xb = x + (size_t)b * Cc * Nn;
    #pragma unroll
    for (int it = 0; it < 16; ++it) {
        int c = ((t >> 6) + it * 4) * 2;
        int n = t & 63;
        BPack p;
        p.h[0] = (bf16_t)xb[(size_t)c * Nn + n0 + n];
        p.h[1] = (bf16_t)xb[(size_t)(c + 1) * Nn + n0 + n];
        unsigned byte = n * 256 + ((unsigned)(c * 2) ^ ((n & 7) << 4));
        *(unsigned*)(smem + byte) = p.u;
    }
    const float* wpg = Wp + (size_t)h * 96 * Cc;
    #pragma unroll
    for (int it = 0; it < 24; ++it) {
        int idx = t + it * 256;
        int row = idx >> 6;
        int col = (idx & 63) * 2;
        BPack p;
        p.h[0] = (bf16_t)wpg[row * Cc + col];
        p.h[1] = (bf16_t)wpg[row * Cc + col + 1];
        unsigned byte = 16384 + row * 256 + ((unsigned)(col * 2) ^ ((row & 7) << 4));
        *(unsigned*)(smem + byte) = p.u;
    }
    __syncthreads();

    f32x4 acc[6] = {};
    #pragma unroll
    for (int kc = 0; kc < 4; ++kc) {
        int cb = (kc * 32 + g * 8) * 2;
        int rowA = w * 16 + a;
        bf16x8 af = *(const bf16x8*)(smem + rowA * 256 + (cb ^ ((rowA & 7) << 4)));
        #pragma unroll
        for (int pt = 0; pt < 6; ++pt) {
            int rowB = pt * 16 + a;
            bf16x8 bfr = *(const bf16x8*)(smem + 16384 + rowB * 256 + (cb ^ ((rowB & 7) << 4)));
            acc[pt] = MFMA16(af, bfr, acc[pt]);
        }
    }

    const int bh = b * NH + h;
    #pragma unroll
    for (int pt = 0; pt < 4; ++pt) {
        const int which = pt >> 1;
        const int d = (pt & 1) * 16 + a;
        const float bias = bp[h * 96 + which * 32 + d];
        bf16_t* dst = which ? k_s : q_s;
        const float sc = which ? 1.0f : QSCALE;
        #pragma unroll
        for (int r = 0; r < 4; ++r) {
            int n = n0 + w * 16 + g * 4 + r;
            dst[((size_t)bh * Nn + n) * DK + d] = (bf16_t)((acc[pt][r] + bias) * sc);
        }
    }
    __syncthreads();
    bf16_t* vt_l = (bf16_t*)smem;
    #pragma unroll
    for (int pt = 4; pt < 6; ++pt) {
        const int d = (pt & 1) * 16 + a;
        const float bias = bp[h * 96 + 64 + d];
        #pragma unroll
        for (int r = 0; r < 4; ++r) {
            int nl = w * 16 + g * 4 + r;
            vt_l[d * 72 + nl] = (bf16_t)(acc[pt][r] + bias);
        }
    }
    __syncthreads();
    #pragma unroll
    for (int it = 0; it < 8; ++it) {
        int idx = t + it * 256;
        int d = idx >> 6, n = idx & 63;
        int m = n & 31;
        int col = ((m & 15) << 1) | (m >> 4);
        int jj = (n & 32) | col;
        vt_s[((size_t)bh * DK + d) * Nn + n0 + jj] = vt_l[d * 72 + n];
    }
}

// ---------------------------------------------------------------------------
// K2: partial column sums. S_part[is][bh][j] = sum_{i in split is} 2^t[i,j].
// Grid: 16bh x 32jchunk x 4isplit = 2048 blocks -> ~8 blocks/CU.
// ---------------------------------------------------------------------------
__global__ __launch_bounds__(256) void k_stats(const bf16_t* __restrict__ q_s,
                                               const bf16_t* __restrict__ k_s,
                                               float* __restrict__ S_part)
{
    const int bx = blockIdx.x;
    const int is = bx & 3;
    const int jc = (bx >> 2) & 31;
    const int bh = bx >> 7;
    const int t = threadIdx.x, w = t >> 6, lane = t & 63, a = lane & 15, g = lane >> 4;
    const bf16_t* Q = q_s + (size_t)bh * Nn * DK;
    const bf16_t* K = k_s + (size_t)bh * Nn * DK;
    const int jb = jc * 128 + w * 32;
    bf16x8 kf0 = *(const bf16x8*)(K + (jb + a) * DK + g * 8);
    bf16x8 kf1 = *(const bf16x8*)(K + (jb + 16 + a) * DK + g * 8);
    f32x4 l0 = {}, l1 = {};
    const int ilo = is * (Nn / 4);
    #pragma unroll 4
    for (int i0 = ilo; i0 < ilo + Nn / 4; i0 += 16) {
        bf16x8 qf = *(const bf16x8*)(Q + (i0 + a) * DK + g * 8);
        f32x4 z = {};
        f32x4 t0 = MFMA16(qf, kf0, z);
        f32x4 t1 = MFMA16(qf, kf1, z);
        #pragma unroll
        for (int r = 0; r < 4; ++r) {
            l0[r] += exp2_f(t0[r]);
            l1[r] += exp2_f(t1[r]);
        }
    }
    float s0 = l0[0] + l0[1] + l0[2] + l0[3];
    float s1 = l1[0] + l1[1] + l1[2] + l1[3];
    s0 += __shfl_xor(s0, 16);
    s0 += __shfl_xor(s0, 32);
    s1 += __shfl_xor(s1, 16);
    s1 += __shfl_xor(s1, 32);
    if (g == 0) {
        float* Sp = S_part + ((size_t)is * 16 + bh) * Nn;
        Sp[jb + a]      = s0;
        Sp[jb + 16 + a] = s1;
    }
}

// ---------------------------------------------------------------------------
// K2b: S_j = sum of 4 partials; scale vt_s rows in place by 1/S[p(J)].
// After this, attention weights are just 2^t (no per-j normalization needed).
// ---------------------------------------------------------------------------
__global__ __launch_bounds__(256) void k_vscale(const float* __restrict__ S_part,
                                                bf16_t* __restrict__ vt_s)
{
    __shared__ float sinv[512];
    const int Jb = blockIdx.x;   // 0..7, 512 J each
    const int bh = blockIdx.y;   // 0..15
    const int t = threadIdx.x;
    if (t < 128) {
        #pragma unroll
        for (int k2 = 0; k2 < 4; ++k2) {
            int Jl = t * 4 + k2;
            int m = Jl & 31;
            int pJ = (Jl & ~31) | (m >> 1) | ((m & 1) << 4);  // inverse of k_qkv's store permutation
            int J = Jb * 512 + pJ;
            float s = 0.f;
            #pragma unroll
            for (int is = 0; is < 4; ++is)
                s += S_part[((size_t)is * 16 + bh) * Nn + J];
            sinv[Jl] = 1.0f / s;
        }
    }
    __syncthreads();
    bf16_t* vrow = vt_s + (size_t)bh * DK * Nn;
    #pragma unroll
    for (int it = 0; it < 8; ++it) {
        int idx = t + it * 256;
        int d = idx >> 6, Jg = (idx & 63) * 8;
        bf16_t* p = vrow + (size_t)d * Nn + Jb * 512 + Jg;
        bf16x8 v = *(const bf16x8*)p;
        #pragma unroll
        for (int k2 = 0; k2 < 8; ++k2) v[k2] = (bf16_t)((float)v[k2] * sinv[Jg + k2]);
        *(bf16x8*)p = v;
    }
}

// ---------------------------------------------------------------------------
// K3: O[i,d] = sum_j 2^t[i,j] * V'[j,d], j-split NJS ways into f32 partials.
// Grid: 16bh x 32ichunk x NJS. P: D-layout -> per-wave LDS -> A-fragment,
// j pair-permutation cancels against vt_s storage permutation.
// ---------------------------------------------------------------------------
__global__ __launch_bounds__(256) void k_attn(const bf16_t* __restrict__ q_s,
                                              const bf16_t* __restrict__ k_s,
                                              const bf16_t* __restrict__ vt_s,
                                              float* __restrict__ opart,
                                              int NJS, int jspan)
{
    __shared__ __attribute__((aligned(16))) bf16_t p_lds[4][32][40];
    const int bx = blockIdx.x;
    const int js = bx % NJS;
    const int ic = (bx / NJS) & 31;
    const int bh = bx / (NJS * 32);
    const int b = bh >> 2, h = bh & 3;
    const int i0 = ic * 128;
    const int t = threadIdx.x, w = t >> 6, lane = t & 63, a = lane & 15, g = lane >> 4;
    const bf16_t* Q  = q_s  + (size_t)bh * Nn * DK;
    const bf16_t* K  = k_s  + (size_t)bh * Nn * DK;
    const bf16_t* Vt = vt_s + (size_t)bh * DK * Nn;
    const int ib = i0 + w * 32;
    bf16x8 qf0 = *(const bf16x8*)(Q + (ib + a) * DK + g * 8);
    bf16x8 qf1 = *(const bf16x8*)(Q + (ib + 16 + a) * DK + g * 8);
    f32x4 o00 = {}, o01 = {}, o10 = {}, o11 = {};
    const int jlo = js * jspan;
    for (int j0 = jlo; j0 < jlo + jspan; j0 += 32) {
        bf16x8 kf0 = *(const bf16x8*)(K + (j0 + a) * DK + g * 8);
        bf16x8 kf1 = *(const bf16x8*)(K + (j0 + 16 + a) * DK + g * 8);
        f32x4 z = {};
        f32x4 s00 = MFMA16(qf0, kf0, z);
        f32x4 s01 = MFMA16(qf0, kf1, z);
        f32x4 s10 = MFMA16(qf1, kf0, z);
        f32x4 s11 = MFMA16(qf1, kf1, z);
        #pragma unroll
        for (int r = 0; r < 4; ++r) {
            BPack pA; pA.h[0] = (bf16_t)exp2_f(s00[r]); pA.h[1] = (bf16_t)exp2_f(s01[r]);
            *(unsigned*)&p_lds[w][g * 4 + r][2 * a] = pA.u;
            BPack pB; pB.h[0] = (bf16_t)exp2_f(s10[r]); pB.h[1] = (bf16_t)exp2_f(s11[r]);
            *(unsigned*)&p_lds[w][16 + g * 4 + r][2 * a] = pB.u;
        }
        bf16x8 pa0 = *(const bf16x8*)&p_lds[w][a][g * 8];
        bf16x8 pa1 = *(const bf16x8*)&p_lds[w][16 + a][g * 8];
        bf16x8 vf0 = *(const bf16x8*)(Vt + (size_t)a * Nn + j0 + g * 8);
        bf16x8 vf1 = *(const bf16x8*)(Vt + (size_t)(16 + a) * Nn + j0 + g * 8);
        o00 = MFMA16(pa0, vf0, o00);
        o01 = MFMA16(pa0, vf1, o01);
        o10 = MFMA16(pa1, vf0, o10);
        o11 = MFMA16(pa1, vf1, o11);
    }
    float* Ob = opart + ((size_t)(js * Bn + b) * Nn) * 128 + h * DK;
    #pragma unroll
    for (int r = 0; r < 4; ++r) {
        int n0a = i0 + w * 32 + g * 4 + r;
        int n1a = n0a + 16;
        Ob[(size_t)n0a * 128 + a]      = o00[r];
        Ob[(size_t)n0a * 128 + 16 + a] = o01[r];
        Ob[(size_t)n1a * 128 + a]      = o10[r];
        Ob[(size_t)n1a * 128 + 16 + a] = o11[r];
    }
}

// ---------------------------------------------------------------------------
// K4: out[b][c][n] = ((sum_js opart) @ Wo^T)[n][c] + bo[c] + x[b][c][n]
// ---------------------------------------------------------------------------
__global__ __launch_bounds__(256) void k_out(const float* __restrict__ opart,
                                             const float* __restrict__ Wo,
                                             const float* __restrict__ bo,
                                             const float* __restrict__ x,
                                             float* __restrict__ out,
                                             int NJS)
{
    __shared__ __attribute__((aligned(16))) char smem[33280]; // Wo bf16 32KB, then out_t [128][65] f32
    const int n0 = blockIdx.x * 64;
    const int b = blockIdx.y;
    const int t = threadIdx.x, w = t >> 6, lane = t & 63, a = lane & 15, g = lane >> 4;
    #pragma unroll
    for (int it = 0; it < 32; ++it) {
        int idx = t + it * 256;
        int row = idx >> 6;
        int col = (idx & 63) * 2;
        BPack p;
        p.h[0] = (bf16_t)Wo[row * 128 + col];
        p.h[1] = (bf16_t)Wo[row * 128 + col + 1];
        unsigned byte = row * 256 + ((unsigned)(col * 2) ^ ((row & 7) << 4));
        *(unsigned*)(smem + byte) = p.u;
    }
    __syncthreads();
    const size_t OSTRIDE = (size_t)Bn * Nn * 128;
    const float* Ob = opart + ((size_t)b * Nn + n0 + w * 16 + a) * 128;
    f32x4 acc[8] = {};
    #pragma unroll
    for (int kc = 0; kc < 4; ++kc) {
        f32x4 sA = {}, sB = {};
        for (int js = 0; js < NJS; ++js) {
            const float* pp = Ob + (size_t)js * OSTRIDE + kc * 32 + g * 8;
            sA += *(const f32x4*)pp;
            sB += *(const f32x4*)(pp + 4);
        }
        bf16x8 af;
        #pragma unroll
        for (int k2 = 0; k2 < 4; ++k2) {
            af[k2]     = (bf16_t)sA[k2];
            af[k2 + 4] = (bf16_t)sB[k2];
        }
        int cb = (kc * 32 + g * 8) * 2;
        #pragma unroll
        for (int ct = 0; ct < 8; ++ct) {
            int rowB = ct * 16 + a;
            bf16x8 bfr = *(const bf16x8*)(smem + rowB * 256 + (cb ^ ((rowB & 7) << 4)));
            acc[ct] = MFMA16(af, bfr, acc[ct]);
        }
    }
    __syncthreads();
    float* out_t = (float*)smem;   // [128][65]
    #pragma unroll
    for (int ct = 0; ct < 8; ++ct) {
        int c = ct * 16 + a;
        #pragma unroll
        for (int r = 0; r < 4; ++r) {
            out_t[c * 65 + w * 16 + g * 4 + r] = acc[ct][r];
        }
    }
    __syncthreads();
    const float* xb = x + (size_t)b * Cc * Nn;
    #pragma unroll
    for (int it = 0; it < 32; ++it) {
        int idx = t + it * 256;
        int c = idx >> 6, n = idx & 63;
        out[((size_t)b * Cc + c) * Nn + n0 + n] = out_t[c * 65 + n] + xb[(size_t)c * Nn + n0 + n] + bo[c];
    }
}

extern "C" void kernel_launch(void* const* d_in, const int* in_sizes, int n_in,
                              void* d_out, int out_size, void* d_ws, size_t ws_size,
                              hipStream_t stream)
{
    const float* x  = (const float*)d_in[0];
    const float* Wp = (const float*)d_in[1];
    const float* bp = (const float*)d_in[2];
    const float* Wo = (const float*)d_in[3];
    const float* bo = (const float*)d_in[4];
    float* out = (float*)d_out;

    char* ws = (char*)d_ws;
    bf16_t* q_s   = (bf16_t*)(ws);                 // 4 MB
    bf16_t* k_s   = (bf16_t*)(ws + (4  << 20));    // 4 MB
    bf16_t* vt_s  = (bf16_t*)(ws + (8  << 20));    // 4 MB
    float*  S_part= (float*) (ws + (12 << 20));    // 1 MB (4 splits x 16bh x 4096 f32)
    float*  opart = (float*) (ws + (13 << 20));    // NJS x 8 MB

    // pick j-split factor by available workspace (deterministic across calls)
    const size_t base = 13ull << 20;
    const size_t plane = 8ull << 20;
    int NJS = 1;
    if (ws_size >= base + 4 * plane) NJS = 4;
    else if (ws_size >= base + 2 * plane) NJS = 2;
    const int jspan = Nn / NJS;

    k_qkv   <<<dim3(Nn / 64, Bn, NH),   256, 0, stream>>>(x, Wp, bp, q_s, k_s, vt_s);
    k_stats <<<16 * 32 * 4,             256, 0, stream>>>(q_s, k_s, S_part);
    k_vscale<<<dim3(8, 16),             256, 0, stream>>>(S_part, vt_s);
    k_attn  <<<16 * 32 * NJS,           256, 0, stream>>>(q_s, k_s, vt_s, opart, NJS, jspan);
    k_out   <<<dim3(Nn / 64, Bn),       256, 0, stream>>>(opart, Wo, bo, x, out, NJS);
}

// Round 4
// 230.129 us; speedup vs baseline: 1.0835x; 1.0029x over previous
//
#include <hip/hip_runtime.h>

typedef __bf16 bf16_t;
typedef __bf16 bf16x8 __attribute__((ext_vector_type(8)));
typedef float  f32x4  __attribute__((ext_vector_type(4)));

#define MFMA16(a, b, c) __builtin_amdgcn_mfma_f32_16x16x32_bf16((a), (b), (c), 0, 0, 0)

__device__ __forceinline__ float exp2_f(float x) { return __builtin_amdgcn_exp2f(x); }

union BPack { bf16_t h[2]; unsigned u; };

constexpr int Bn = 4, Cc = 128, Nn = 4096, NH = 4, DK = 32;
// fold 1/sqrt(32) * log2(e) into stored Q so MFMA emits exp2-domain logits
constexpr float QSCALE = 0.176776695f * 1.44269504f;

// ---------------------------------------------------------------------------
// K1: fused transpose + QKV projection.
//   v -> vt_s[bh][d][J] transposed; stored value at J is V[p(J)],
//   p(J)=(J&~31)+((J&31)>>1)+((J&1)*16)  (matches MFMA A/B k-slot interleave)
// ---------------------------------------------------------------------------
__global__ __launch_bounds__(256) void k_qkv(const float* __restrict__ x,
                                             const float* __restrict__ Wp,
                                             const float* __restrict__ bp,
                                             bf16_t* __restrict__ q_s,
                                             bf16_t* __restrict__ k_s,
                                             bf16_t* __restrict__ vt_s)
{
    __shared__ __attribute__((aligned(16))) char smem[40960]; // xs 16KB + wp 24KB
    const int n0 = blockIdx.x * 64;
    const int b  = blockIdx.y;
    const int h  = blockIdx.z;
    const int t  = threadIdx.x;
    const int w = t >> 6, lane = t & 63, a = lane & 15, g = lane >> 4;

    const float* xb = x + (size_t)b * Cc * Nn;
    #pragma unroll
    for (int it = 0; it < 16; ++it) {
        int c = ((t >> 6) + it * 4) * 2;
        int n = t & 63;
        BPack p;
        p.h[0] = (bf16_t)xb[(size_t)c * Nn + n0 + n];
        p.h[1] = (bf16_t)xb[(size_t)(c + 1) * Nn + n0 + n];
        unsigned byte = n * 256 + ((unsigned)(c * 2) ^ ((n & 7) << 4));
        *(unsigned*)(smem + byte) = p.u;
    }
    const float* wpg = Wp + (size_t)h * 96 * Cc;
    #pragma unroll
    for (int it = 0; it < 24; ++it) {
        int idx = t + it * 256;
        int row = idx >> 6;
        int col = (idx & 63) * 2;
        BPack p;
        p.h[0] = (bf16_t)wpg[row * Cc + col];
        p.h[1] = (bf16_t)wpg[row * Cc + col + 1];
        unsigned byte = 16384 + row * 256 + ((unsigned)(col * 2) ^ ((row & 7) << 4));
        *(unsigned*)(smem + byte) = p.u;
    }
    __syncthreads();

    f32x4 acc[6] = {};
    #pragma unroll
    for (int kc = 0; kc < 4; ++kc) {
        int cb = (kc * 32 + g * 8) * 2;
        int rowA = w * 16 + a;
        bf16x8 af = *(const bf16x8*)(smem + rowA * 256 + (cb ^ ((rowA & 7) << 4)));
        #pragma unroll
        for (int pt = 0; pt < 6; ++pt) {
            int rowB = pt * 16 + a;
            bf16x8 bfr = *(const bf16x8*)(smem + 16384 + rowB * 256 + (cb ^ ((rowB & 7) << 4)));
            acc[pt] = MFMA16(af, bfr, acc[pt]);
        }
    }

    const int bh = b * NH + h;
    #pragma unroll
    for (int pt = 0; pt < 4; ++pt) {
        const int which = pt >> 1;
        const int d = (pt & 1) * 16 + a;
        const float bias = bp[h * 96 + which * 32 + d];
        bf16_t* dst = which ? k_s : q_s;
        const float sc = which ? 1.0f : QSCALE;
        #pragma unroll
        for (int r = 0; r < 4; ++r) {
            int n = n0 + w * 16 + g * 4 + r;
            dst[((size_t)bh * Nn + n) * DK + d] = (bf16_t)((acc[pt][r] + bias) * sc);
        }
    }
    __syncthreads();
    bf16_t* vt_l = (bf16_t*)smem;
    #pragma unroll
    for (int pt = 4; pt < 6; ++pt) {
        const int d = (pt & 1) * 16 + a;
        const float bias = bp[h * 96 + 64 + d];
        #pragma unroll
        for (int r = 0; r < 4; ++r) {
            int nl = w * 16 + g * 4 + r;
            vt_l[d * 72 + nl] = (bf16_t)(acc[pt][r] + bias);
        }
    }
    __syncthreads();
    #pragma unroll
    for (int it = 0; it < 8; ++it) {
        int idx = t + it * 256;
        int d = idx >> 6, n = idx & 63;
        int m = n & 31;
        int col = ((m & 15) << 1) | (m >> 4);
        int jj = (n & 32) | col;
        vt_s[((size_t)bh * DK + d) * Nn + n0 + jj] = vt_l[d * 72 + n];
    }
}

// ---------------------------------------------------------------------------
// K2: partial column sums. S_part[is][bh][j] = sum_{i in split is} 2^t[i,j].
// ---------------------------------------------------------------------------
__global__ __launch_bounds__(256) void k_stats(const bf16_t* __restrict__ q_s,
                                               const bf16_t* __restrict__ k_s,
                                               float* __restrict__ S_part)
{
    const int bx = blockIdx.x;
    const int is = bx & 3;
    const int jc = (bx >> 2) & 31;
    const int bh = bx >> 7;
    const int t = threadIdx.x, w = t >> 6, lane = t & 63, a = lane & 15, g = lane >> 4;
    const bf16_t* Q = q_s + (size_t)bh * Nn * DK;
    const bf16_t* K = k_s + (size_t)bh * Nn * DK;
    const int jb = jc * 128 + w * 32;
    bf16x8 kf0 = *(const bf16x8*)(K + (jb + a) * DK + g * 8);
    bf16x8 kf1 = *(const bf16x8*)(K + (jb + 16 + a) * DK + g * 8);
    f32x4 l0 = {}, l1 = {};
    const int ilo = is * (Nn / 4);
    #pragma unroll 4
    for (int i0 = ilo; i0 < ilo + Nn / 4; i0 += 16) {
        bf16x8 qf = *(const bf16x8*)(Q + (i0 + a) * DK + g * 8);
        f32x4 z = {};
        f32x4 t0 = MFMA16(qf, kf0, z);
        f32x4 t1 = MFMA16(qf, kf1, z);
        #pragma unroll
        for (int r = 0; r < 4; ++r) {
            l0[r] += exp2_f(t0[r]);
            l1[r] += exp2_f(t1[r]);
        }
    }
    float s0 = l0[0] + l0[1] + l0[2] + l0[3];
    float s1 = l1[0] + l1[1] + l1[2] + l1[3];
    s0 += __shfl_xor(s0, 16);
    s0 += __shfl_xor(s0, 32);
    s1 += __shfl_xor(s1, 16);
    s1 += __shfl_xor(s1, 32);
    if (g == 0) {
        float* Sp = S_part + ((size_t)is * 16 + bh) * Nn;
        Sp[jb + a]      = s0;
        Sp[jb + 16 + a] = s1;
    }
}

// ---------------------------------------------------------------------------
// K2b: S_j = sum of 4 partials; scale vt_s rows in place by 1/S[p(J)].
// ---------------------------------------------------------------------------
__global__ __launch_bounds__(256) void k_vscale(const float* __restrict__ S_part,
                                                bf16_t* __restrict__ vt_s)
{
    __shared__ float sinv[512];
    const int Jb = blockIdx.x;   // 0..7, 512 J each
    const int bh = blockIdx.y;   // 0..15
    const int t = threadIdx.x;
    if (t < 128) {
        #pragma unroll
        for (int k2 = 0; k2 < 4; ++k2) {
            int Jl = t * 4 + k2;
            int m = Jl & 31;
            int pJ = (Jl & ~31) | (m >> 1) | ((m & 1) << 4);  // inverse of k_qkv's store permutation
            int J = Jb * 512 + pJ;
            float s = 0.f;
            #pragma unroll
            for (int is = 0; is < 4; ++is)
                s += S_part[((size_t)is * 16 + bh) * Nn + J];
            sinv[Jl] = 1.0f / s;
        }
    }
    __syncthreads();
    bf16_t* vrow = vt_s + (size_t)bh * DK * Nn;
    #pragma unroll
    for (int it = 0; it < 8; ++it) {
        int idx = t + it * 256;
        int d = idx >> 6, Jg = (idx & 63) * 8;
        bf16_t* p = vrow + (size_t)d * Nn + Jb * 512 + Jg;
        bf16x8 v = *(const bf16x8*)p;
        #pragma unroll
        for (int k2 = 0; k2 < 8; ++k2) v[k2] = (bf16_t)((float)v[k2] * sinv[Jg + k2]);
        *(bf16x8*)p = v;
    }
}

// ---------------------------------------------------------------------------
// K3: O[i,d] = sum_j 2^t[i,j] * V'[j,d], j-split into f32 partials.
// SWAPPED QK^T: S^T = MFMA(K,Q) puts i on the col axis (col=a -> i=a), so
// each lane holds exactly its PV A-fragment row. The even/odd interleave of
// the two j-tiles reproduces the k-slot permutation p(c) that vt_s storage
// uses -> P never leaves registers, no LDS, no shuffles.
// ---------------------------------------------------------------------------
template<int JSPAN>
__global__ __launch_bounds__(256) void k_attn(const bf16_t* __restrict__ q_s,
                                              const bf16_t* __restrict__ k_s,
                                              const bf16_t* __restrict__ vt_s,
                                              float* __restrict__ opart)
{
    constexpr int NJS = Nn / JSPAN;
    const int bx = blockIdx.x;
    const int js = bx % NJS;
    const int ic = (bx / NJS) & 31;
    const int bh = bx / (NJS * 32);
    const int b = bh >> 2, h = bh & 3;
    const int i0 = ic * 128;
    const int t = threadIdx.x, w = t >> 6, lane = t & 63, a = lane & 15, g = lane >> 4;
    const bf16_t* Q  = q_s  + (size_t)bh * Nn * DK;
    const bf16_t* K  = k_s  + (size_t)bh * Nn * DK;
    const bf16_t* Vt = vt_s + (size_t)bh * DK * Nn;
    const int ib = i0 + w * 32;
    bf16x8 qf0 = *(const bf16x8*)(Q + (ib + a) * DK + g * 8);
    bf16x8 qf1 = *(const bf16x8*)(Q + (ib + 16 + a) * DK + g * 8);
    f32x4 o00 = {}, o01 = {}, o10 = {}, o11 = {};
    const int jlo = js * JSPAN;
    #pragma unroll 2
    for (int j0 = jlo; j0 < jlo + JSPAN; j0 += 32) {
        bf16x8 kf0 = *(const bf16x8*)(K + (j0 + a) * DK + g * 8);
        bf16x8 kf1 = *(const bf16x8*)(K + (j0 + 16 + a) * DK + g * 8);
        bf16x8 vf0 = *(const bf16x8*)(Vt + (size_t)a * Nn + j0 + g * 8);
        bf16x8 vf1 = *(const bf16x8*)(Vt + (size_t)(16 + a) * Nn + j0 + g * 8);
        f32x4 z = {};
        f32x4 sT00 = MFMA16(kf0, qf0, z);   // j-tile0 rows, i-tile0 cols
        f32x4 sT10 = MFMA16(kf1, qf0, z);   // j-tile1 rows, i-tile0 cols
        f32x4 sT01 = MFMA16(kf0, qf1, z);
        f32x4 sT11 = MFMA16(kf1, qf1, z);
        bf16x8 pa0, pa1;
        #pragma unroll
        for (int r = 0; r < 4; ++r) {
            pa0[2 * r]     = (bf16_t)exp2_f(sT00[r]);
            pa0[2 * r + 1] = (bf16_t)exp2_f(sT10[r]);
            pa1[2 * r]     = (bf16_t)exp2_f(sT01[r]);
            pa1[2 * r + 1] = (bf16_t)exp2_f(sT11[r]);
        }
        o00 = MFMA16(pa0, vf0, o00);
        o01 = MFMA16(pa0, vf1, o01);
        o10 = MFMA16(pa1, vf0, o10);
        o11 = MFMA16(pa1, vf1, o11);
    }
    float* Ob = opart + ((size_t)(js * Bn + b) * Nn) * 128 + h * DK;
    #pragma unroll
    for (int r = 0; r < 4; ++r) {
        int n0a = i0 + w * 32 + g * 4 + r;
        int n1a = n0a + 16;
        Ob[(size_t)n0a * 128 + a]      = o00[r];
        Ob[(size_t)n0a * 128 + 16 + a] = o01[r];
        Ob[(size_t)n1a * 128 + a]      = o10[r];
        Ob[(size_t)n1a * 128 + 16 + a] = o11[r];
    }
}

// ---------------------------------------------------------------------------
// K4: out[b][c][n] = ((sum_js opart) @ Wo^T)[n][c] + bo[c] + x[b][c][n]
// ---------------------------------------------------------------------------
__global__ __launch_bounds__(256) void k_out(const float* __restrict__ opart,
                                             const float* __restrict__ Wo,
                                             const float* __restrict__ bo,
                                             const float* __restrict__ x,
                                             float* __restrict__ out,
                                             int NJS)
{
    __shared__ __attribute__((aligned(16))) char smem[33280]; // Wo bf16 32KB, then out_t [128][65] f32
    const int n0 = blockIdx.x * 64;
    const int b = blockIdx.y;
    const int t = threadIdx.x, w = t >> 6, lane = t & 63, a = lane & 15, g = lane >> 4;
    #pragma unroll
    for (int it = 0; it < 32; ++it) {
        int idx = t + it * 256;
        int row = idx >> 6;
        int col = (idx & 63) * 2;
        BPack p;
        p.h[0] = (bf16_t)Wo[row * 128 + col];
        p.h[1] = (bf16_t)Wo[row * 128 + col + 1];
        unsigned byte = row * 256 + ((unsigned)(col * 2) ^ ((row & 7) << 4));
        *(unsigned*)(smem + byte) = p.u;
    }
    __syncthreads();
    const size_t OSTRIDE = (size_t)Bn * Nn * 128;
    const float* Ob = opart + ((size_t)b * Nn + n0 + w * 16 + a) * 128;
    f32x4 acc[8] = {};
    #pragma unroll
    for (int kc = 0; kc < 4; ++kc) {
        f32x4 sA = {}, sB = {};
        for (int js = 0; js < NJS; ++js) {
            const float* pp = Ob + (size_t)js * OSTRIDE + kc * 32 + g * 8;
            sA += *(const f32x4*)pp;
            sB += *(const f32x4*)(pp + 4);
        }
        bf16x8 af;
        #pragma unroll
        for (int k2 = 0; k2 < 4; ++k2) {
            af[k2]     = (bf16_t)sA[k2];
            af[k2 + 4] = (bf16_t)sB[k2];
        }
        int cb = (kc * 32 + g * 8) * 2;
        #pragma unroll
        for (int ct = 0; ct < 8; ++ct) {
            int rowB = ct * 16 + a;
            bf16x8 bfr = *(const bf16x8*)(smem + rowB * 256 + (cb ^ ((rowB & 7) << 4)));
            acc[ct] = MFMA16(af, bfr, acc[ct]);
        }
    }
    __syncthreads();
    float* out_t = (float*)smem;   // [128][65]
    #pragma unroll
    for (int ct = 0; ct < 8; ++ct) {
        int c = ct * 16 + a;
        #pragma unroll
        for (int r = 0; r < 4; ++r) {
            out_t[c * 65 + w * 16 + g * 4 + r] = acc[ct][r];
        }
    }
    __syncthreads();
    const float* xb = x + (size_t)b * Cc * Nn;
    #pragma unroll
    for (int it = 0; it < 32; ++it) {
        int idx = t + it * 256;
        int c = idx >> 6, n = idx & 63;
        out[((size_t)b * Cc + c) * Nn + n0 + n] = out_t[c * 65 + n] + xb[(size_t)c * Nn + n0 + n] + bo[c];
    }
}

extern "C" void kernel_launch(void* const* d_in, const int* in_sizes, int n_in,
                              void* d_out, int out_size, void* d_ws, size_t ws_size,
                              hipStream_t stream)
{
    const float* x  = (const float*)d_in[0];
    const float* Wp = (const float*)d_in[1];
    const float* bp = (const float*)d_in[2];
    const float* Wo = (const float*)d_in[3];
    const float* bo = (const float*)d_in[4];
    float* out = (float*)d_out;

    char* ws = (char*)d_ws;
    bf16_t* q_s   = (bf16_t*)(ws);                 // 4 MB
    bf16_t* k_s   = (bf16_t*)(ws + (4  << 20));    // 4 MB
    bf16_t* vt_s  = (bf16_t*)(ws + (8  << 20));    // 4 MB
    float*  S_part= (float*) (ws + (12 << 20));    // 1 MB (4 splits x 16bh x 4096 f32)
    float*  opart = (float*) (ws + (13 << 20));    // NJS x 8 MB

    const size_t base = 13ull << 20;
    const size_t plane = 8ull << 20;
    int NJS = 1;
    if (ws_size >= base + 4 * plane) NJS = 4;
    else if (ws_size >= base + 2 * plane) NJS = 2;

    k_qkv   <<<dim3(Nn / 64, Bn, NH),   256, 0, stream>>>(x, Wp, bp, q_s, k_s, vt_s);
    k_stats <<<16 * 32 * 4,             256, 0, stream>>>(q_s, k_s, S_part);
    k_vscale<<<dim3(8, 16),             256, 0, stream>>>(S_part, vt_s);
    if (NJS == 4)      k_attn<1024><<<16 * 32 * 4, 256, 0, stream>>>(q_s, k_s, vt_s, opart);
    else if (NJS == 2) k_attn<2048><<<16 * 32 * 2, 256, 0, stream>>>(q_s, k_s, vt_s, opart);
    else               k_attn<4096><<<16 * 32 * 1, 256, 0, stream>>>(q_s, k_s, vt_s, opart);
    k_out   <<<dim3(Nn / 64, Bn),       256, 0, stream>>>(opart, Wo, bo, x, out, NJS);
}